// Round 1
// baseline (313.912 us; speedup 1.0000x reference)
//
#include <hip/hip_runtime.h>

// NMS + farthest-pair + Voronoi masks, B=131072 heatmaps of 14x14 fp32.
// One 64-lane wave per batch. Lane i owns flat indices {i, i+64, i+128, i+192(<4 only)}.
// Memory-bound: ~103 MB read + ~205 MB write.

constexpr int L = 14;
constexpr int NPIX = L * L;   // 196

__global__ __launch_bounds__(256) void nms_kernel(const float* __restrict__ hm,
                                                  float* __restrict__ out,
                                                  int B) {
    const int lane = threadIdx.x & 63;
    const int b = (blockIdx.x << 2) + (threadIdx.x >> 6);
    if (b >= B) return;

    const float* __restrict__ base = hm + (size_t)b * NPIX;

    const int k0 = lane;
    const int k1 = lane + 64;
    const int k2 = lane + 128;
    const int k3 = lane + 192;            // valid only for lane < 4
    const bool has3 = (lane < 4);

    float v0 = base[k0];
    float v1 = base[k1];
    float v2 = base[k2];
    float v3 = has3 ? base[k3] : -1.0f;   // -1 sentinel: never wins argmax (heat >= 0)

    const float TH = 0.6f;                // matches jnp float32 weak-typed 0.6
    v0 = (v0 > TH) ? v0 : 0.0f;
    v1 = (v1 > TH) ? v1 : 0.0f;
    v2 = (v2 > TH) ? v2 : 0.0f;
    if (has3) v3 = (v3 > TH) ? v3 : 0.0f;

    // per-element (row, col), computed once
    const int x0 = k0 / L, y0 = k0 % L;
    const int x1e = k1 / L, y1e = k1 % L;
    const int x2e = k2 / L, y2e = k2 % L;
    const int x3e = k3 / L, y3e = k3 % L;

    int idxs[4];
#pragma unroll
    for (int r = 0; r < 4; ++r) {
        // within-lane argmax, first-index-wins (strict >)
        float bv = v0; int bk = k0;
        if (v1 > bv) { bv = v1; bk = k1; }
        if (v2 > bv) { bv = v2; bk = k2; }
        if (v3 > bv) { bv = v3; bk = k3; }
        // wave butterfly: lexicographic max on (value desc, index asc) -> all lanes converge
#pragma unroll
        for (int off = 32; off; off >>= 1) {
            float ov = __shfl_xor(bv, off, 64);
            int   ok = __shfl_xor(bk, off, 64);
            if (ov > bv || (ov == bv && ok < bk)) { bv = ov; bk = ok; }
        }
        idxs[r] = bk;
        if (r < 3) {
            // suppress window rows [ax-5, min(ax+5,15)), cols [ay-5, min(ay+5,15))
            const int ax = bk / L, ay = bk % L;
            const int wx1 = max(ax - 5, 0), wx2 = min(ax + 5, 15);
            const int wy1 = max(ay - 5, 0), wy2 = min(ay + 5, 15);
            if (x0  >= wx1 && x0  < wx2 && y0  >= wy1 && y0  < wy2) v0 = 0.0f;
            if (x1e >= wx1 && x1e < wx2 && y1e >= wy1 && y1e < wy2) v1 = 0.0f;
            if (x2e >= wx1 && x2e < wx2 && y2e >= wy1 && y2e < wy2) v2 = 0.0f;
            if (has3 && x3e >= wx1 && x3e < wx2 && y3e >= wy1 && y3e < wy2) v3 = 0.0f;
        }
    }

    // coords of the 4 peaks (int, matches jnp integer math)
    int cx[4], cy[4];
#pragma unroll
    for (int i = 0; i < 4; ++i) { cx[i] = idxs[i] / L; cy[i] = idxs[i] % L; }

    // farthest pair among 6, first-index-wins argmax
    const int pa[6] = {0, 0, 0, 1, 1, 2};
    const int pb[6] = {1, 2, 3, 2, 3, 3};
    int bestd = -1, bi = 0;
#pragma unroll
    for (int p = 0; p < 6; ++p) {
        const int dx = cx[pb[p]] - cx[pa[p]];
        const int dy = cy[pb[p]] - cy[pa[p]];
        const int d = dx * dx + dy * dy;
        if (d > bestd) { bestd = d; bi = p; }
    }
    const int ax0 = cx[pa[bi]], ay0 = cy[pa[bi]];
    const int ax1 = cx[pb[bi]], ay1 = cy[pb[bi]];

    float* __restrict__ o1 = out + (size_t)b * NPIX;
    float* __restrict__ o2 = out + (size_t)B * NPIX + (size_t)b * NPIX;

    // m1 = (d1 < d2) ? 1 : 0 ; m2 = 1 - m1   (all-int distance math)
#define EMIT(X, Y, K)                                                      \
    do {                                                                   \
        const int du1 = (X) - ax0, dv1 = (Y) - ay0;                        \
        const int du2 = (X) - ax1, dv2 = (Y) - ay1;                        \
        const int d1 = du1 * du1 + dv1 * dv1;                              \
        const int d2 = du2 * du2 + dv2 * dv2;                              \
        const float m = (d1 < d2) ? 1.0f : 0.0f;                           \
        o1[(K)] = m;                                                       \
        o2[(K)] = 1.0f - m;                                                \
    } while (0)

    EMIT(x0, y0, k0);
    EMIT(x1e, y1e, k1);
    EMIT(x2e, y2e, k2);
    if (has3) EMIT(x3e, y3e, k3);
#undef EMIT
}

extern "C" void kernel_launch(void* const* d_in, const int* in_sizes, int n_in,
                              void* d_out, int out_size, void* d_ws, size_t ws_size,
                              hipStream_t stream) {
    const float* hm = (const float*)d_in[0];
    float* out = (float*)d_out;
    const int B = in_sizes[0] / NPIX;          // 131072
    const int blocks = (B + 3) / 4;            // 4 waves (batches) per 256-thread block
    nms_kernel<<<blocks, 256, 0, stream>>>(hm, out, B);
}

// Round 2
// 296.836 us; speedup vs baseline: 1.0575x; 1.0575x over previous
//
#include <hip/hip_runtime.h>

// NMS + farthest-pair + Voronoi masks, B=131072 heatmaps of 14x14 fp32.
// One 64-lane wave per batch. Lane l (<49) owns float4 = flat indices 4l..4l+3.
// Argmax = value-only max butterfly (6 shfl + 6 v_max) + ballot/ffs index
// recovery (exact first-occurrence semantics). Memory-bound target:
// ~103 MB read + ~205 MB write  ->  ~49 us at 6.3 TB/s.

constexpr int L = 14;
constexpr int NPIX = L * L;   // 196
constexpr int NV4 = NPIX / 4; // 49 float4 per batch

__global__ __launch_bounds__(256) void nms_kernel(const float4* __restrict__ hm4,
                                                  float4* __restrict__ out4,
                                                  int B) {
    const int lane = threadIdx.x & 63;
    const int b = (blockIdx.x << 2) + (threadIdx.x >> 6);
    if (b >= B) return;

    const bool act = (lane < NV4);

    // one coalesced 16B load per lane (784 B per wave)
    float4 v4;
    if (act) v4 = hm4[(size_t)b * NV4 + lane];
    else     v4 = make_float4(-1.f, -1.f, -1.f, -1.f);  // sentinel: never wins (heat >= 0)

    float va[4] = {v4.x, v4.y, v4.z, v4.w};
    if (act) {
#pragma unroll
        for (int e = 0; e < 4; ++e) va[e] = (va[e] > 0.6f) ? va[e] : 0.0f;
    }

    // per-element coords; sentinel lanes get coords that are never inside any window
    int xs[4], ys[4];
#pragma unroll
    for (int e = 0; e < 4; ++e) {
        const int flat = 4 * lane + e;
        xs[e] = act ? (flat / L) : 1000;
        ys[e] = act ? (flat % L) : 1000;
    }

    int idxs[4];
#pragma unroll
    for (int r = 0; r < 4; ++r) {
        // global max value across the wave (value-only butterfly)
        float mv = fmaxf(fmaxf(va[0], va[1]), fmaxf(va[2], va[3]));
#pragma unroll
        for (int off = 1; off < 64; off <<= 1)
            mv = fmaxf(mv, __shfl_xor(mv, off, 64));

        // first-occurrence index recovery: lowest lane with a match, then
        // lowest element within that lane (flat order = 4*lane + e)
        const bool h0 = (va[0] == mv), h1 = (va[1] == mv),
                   h2 = (va[2] == mv), h3 = (va[3] == mv);
        int e_loc = h0 ? 0 : (h1 ? 1 : (h2 ? 2 : 3));
        const unsigned long long ball = __ballot(h0 | h1 | h2 | h3);
        const int fl = __ffsll(ball) - 1;   // ball != 0: max always comes from an active lane
        const int e0 = __shfl(e_loc, fl, 64);
        const int idx = 4 * fl + e0;
        idxs[r] = idx;

        if (r < 3) {
            // suppress rows [ax-5, min(ax+5,15)), cols [ay-5, min(ay+5,15))
            const int ax = idx / L, ay = idx % L;
            const int wx1 = max(ax - 5, 0), wx2 = min(ax + 5, 15);
            const int wy1 = max(ay - 5, 0), wy2 = min(ay + 5, 15);
#pragma unroll
            for (int e = 0; e < 4; ++e) {
                const bool in = (xs[e] >= wx1) & (xs[e] < wx2) &
                                (ys[e] >= wy1) & (ys[e] < wy2);
                va[e] = in ? 0.0f : va[e];
            }
        }
    }

    // coords of the 4 peaks (int math matches jnp)
    int cx[4], cy[4];
#pragma unroll
    for (int i = 0; i < 4; ++i) { cx[i] = idxs[i] / L; cy[i] = idxs[i] % L; }

    // farthest pair among 6, first-index-wins argmax
    const int pa[6] = {0, 0, 0, 1, 1, 2};
    const int pb[6] = {1, 2, 3, 2, 3, 3};
    int bestd = -1, bi = 0;
#pragma unroll
    for (int p = 0; p < 6; ++p) {
        const int dx = cx[pb[p]] - cx[pa[p]];
        const int dy = cy[pb[p]] - cy[pa[p]];
        const int d = dx * dx + dy * dy;
        if (d > bestd) { bestd = d; bi = p; }
    }
    const int ax0 = cx[pa[bi]], ay0 = cy[pa[bi]];
    const int ax1 = cx[pb[bi]], ay1 = cy[pb[bi]];

    // masks: m1 = (d1 < d2), m2 = 1 - m1 (integer distance math)
    float m1[4], m2[4];
#pragma unroll
    for (int e = 0; e < 4; ++e) {
        const int du1 = xs[e] - ax0, dv1 = ys[e] - ay0;
        const int du2 = xs[e] - ax1, dv2 = ys[e] - ay1;
        const int d1 = du1 * du1 + dv1 * dv1;
        const int d2 = du2 * du2 + dv2 * dv2;
        m1[e] = (d1 < d2) ? 1.0f : 0.0f;
        m2[e] = 1.0f - m1[e];
    }

    if (act) {
        out4[(size_t)b * NV4 + lane] = make_float4(m1[0], m1[1], m1[2], m1[3]);
        out4[(size_t)(B + b) * NV4 + lane] = make_float4(m2[0], m2[1], m2[2], m2[3]);
    }
}

extern "C" void kernel_launch(void* const* d_in, const int* in_sizes, int n_in,
                              void* d_out, int out_size, void* d_ws, size_t ws_size,
                              hipStream_t stream) {
    const float4* hm4 = (const float4*)d_in[0];
    float4* out4 = (float4*)d_out;
    const int B = in_sizes[0] / NPIX;          // 131072
    const int blocks = (B + 3) / 4;            // 4 waves (batches) per 256-thread block
    nms_kernel<<<blocks, 256, 0, stream>>>(hm4, out4, B);
}

// Round 3
// 279.638 us; speedup vs baseline: 1.1226x; 1.0615x over previous
//
#include <hip/hip_runtime.h>

// NMS + farthest-pair + Voronoi masks, B=131072 heatmaps of 14x14 fp32.
// 4 batches per 64-lane wave (16 lanes = 1 DPP row per batch).
// Lane s of a row owns float4 chunks {s, s+16, s+32} (+48 on s==0).
// All cross-lane reduction via DPP (VALU) — zero LDS/DS traffic.
// Memory-bound target: ~103 MB read + ~205 MB write -> ~49 us @ 6.3 TB/s.

constexpr int L = 14;
constexpr int NPIX = L * L;   // 196
constexpr int NV4 = NPIX / 4; // 49

// DPP-based 16-lane (row) reductions: quad_perm xor1, xor2, half_mirror, mirror
template <int CTRL>
__device__ __forceinline__ float dpp_maxf(float x) {
    int y = __builtin_amdgcn_update_dpp(0, __float_as_int(x), CTRL, 0xF, 0xF, true);
    return fmaxf(x, __int_as_float(y));
}
template <int CTRL>
__device__ __forceinline__ int dpp_mini(int x) {
    int y = __builtin_amdgcn_update_dpp(0, x, CTRL, 0xF, 0xF, true);
    return min(x, y);
}
__device__ __forceinline__ float row_max16(float x) {
    x = dpp_maxf<0xB1>(x);   // quad_perm [1,0,3,2]  : xor 1
    x = dpp_maxf<0x4E>(x);   // quad_perm [2,3,0,1]  : xor 2
    x = dpp_maxf<0x141>(x);  // row_half_mirror      : combine quads
    x = dpp_maxf<0x140>(x);  // row_mirror           : combine halves
    return x;
}
__device__ __forceinline__ int row_min16(int x) {
    x = dpp_mini<0xB1>(x);
    x = dpp_mini<0x4E>(x);
    x = dpp_mini<0x141>(x);
    x = dpp_mini<0x140>(x);
    return x;
}

__global__ __launch_bounds__(256) void nms_kernel(const float4* __restrict__ hm4,
                                                  float4* __restrict__ out4,
                                                  int B) {
    const int lane = threadIdx.x & 63;
    const int s = lane & 15;                       // sub-lane within row
    const int b = blockIdx.x * 16 + ((threadIdx.x >> 6) << 2) + (lane >> 4);
    if (b >= B) return;

    const float4* __restrict__ bp = hm4 + (size_t)b * NV4;

    float4 a0 = bp[s];
    float4 a1 = bp[16 + s];
    float4 a2 = bp[32 + s];
    float4 a3 = (s == 0) ? bp[48] : make_float4(-1.f, -1.f, -1.f, -1.f);

    float va[16] = {a0.x, a0.y, a0.z, a0.w, a1.x, a1.y, a1.z, a1.w,
                    a2.x, a2.y, a2.z, a2.w, a3.x, a3.y, a3.z, a3.w};

    // flat(slot i) = 4*s + 64*(i>>2) + (i&3); monotone in i within a lane.
    const int s4 = s << 2;
    int fl[16], px[16];   // flat index, packed (x<<5)|y coords
#pragma unroll
    for (int i = 0; i < 16; ++i) {
        const bool real = (i < 12) || (s == 0);
        fl[i] = s4 + ((i >> 2) << 6) + (i & 3);
        const int x = fl[i] / L, y = fl[i] - x * L;
        px[i] = real ? ((x << 5) | y) : ((31 << 5) | 31);  // sentinel: outside any window
        // threshold; sentinel slots stay -1 (never win, never match mv >= 0)
        va[i] = (va[i] > 0.6f) ? va[i] : (real ? 0.0f : -1.0f);
    }

    int idxs[4];
#pragma unroll
    for (int r = 0; r < 4; ++r) {
        // row-wide max value (pure VALU)
        float mv = va[0];
#pragma unroll
        for (int i = 1; i < 16; ++i) mv = fmaxf(mv, va[i]);
        mv = row_max16(mv);

        // first-occurrence flat index: local lowest matching slot, then row min
        int fc = 1 << 20;
#pragma unroll
        for (int i = 15; i >= 0; --i) fc = (va[i] == mv) ? fl[i] : fc;
        const int idx = row_min16(fc);
        idxs[r] = idx;

        if (r < 3) {
            const int ax = idx / L, ay = idx - (idx / L) * L;
            const int wx1 = max(ax - 5, 0), wx2 = min(ax + 5, 15);
            const int wy1 = max(ay - 5, 0), wy2 = min(ay + 5, 15);
#pragma unroll
            for (int i = 0; i < 16; ++i) {
                const int x = px[i] >> 5, y = px[i] & 31;
                const bool in = (x >= wx1) & (x < wx2) & (y >= wy1) & (y < wy2);
                va[i] = in ? 0.0f : va[i];
            }
        }
    }

    // coords of the 4 peaks (integer math matches jnp)
    int cx[4], cy[4];
#pragma unroll
    for (int i = 0; i < 4; ++i) { cx[i] = idxs[i] / L; cy[i] = idxs[i] - (idxs[i] / L) * L; }

    // farthest pair among 6, first-index-wins argmax
    const int pa[6] = {0, 0, 0, 1, 1, 2};
    const int pb[6] = {1, 2, 3, 2, 3, 3};
    int bestd = -1, bi = 0;
#pragma unroll
    for (int p = 0; p < 6; ++p) {
        const int dx = cx[pb[p]] - cx[pa[p]];
        const int dy = cy[pb[p]] - cy[pa[p]];
        const int d = dx * dx + dy * dy;
        if (d > bestd) { bestd = d; bi = p; }
    }
    const int ax0 = cx[pa[bi]], ay0 = cy[pa[bi]];
    const int ax1 = cx[pb[bi]], ay1 = cy[pb[bi]];

    // Voronoi masks (integer distance math)
    float m[16];
#pragma unroll
    for (int i = 0; i < 16; ++i) {
        const int x = px[i] >> 5, y = px[i] & 31;
        const int du1 = x - ax0, dv1 = y - ay0;
        const int du2 = x - ax1, dv2 = y - ay1;
        m[i] = ((du1 * du1 + dv1 * dv1) < (du2 * du2 + dv2 * dv2)) ? 1.0f : 0.0f;
    }

    float4* __restrict__ o1 = out4 + (size_t)b * NV4;
    float4* __restrict__ o2 = out4 + (size_t)(B + b) * NV4;
    o1[s]      = make_float4(m[0], m[1], m[2], m[3]);
    o1[16 + s] = make_float4(m[4], m[5], m[6], m[7]);
    o1[32 + s] = make_float4(m[8], m[9], m[10], m[11]);
    o2[s]      = make_float4(1.f - m[0], 1.f - m[1], 1.f - m[2], 1.f - m[3]);
    o2[16 + s] = make_float4(1.f - m[4], 1.f - m[5], 1.f - m[6], 1.f - m[7]);
    o2[32 + s] = make_float4(1.f - m[8], 1.f - m[9], 1.f - m[10], 1.f - m[11]);
    if (s == 0) {
        o1[48] = make_float4(m[12], m[13], m[14], m[15]);
        o2[48] = make_float4(1.f - m[12], 1.f - m[13], 1.f - m[14], 1.f - m[15]);
    }
}

extern "C" void kernel_launch(void* const* d_in, const int* in_sizes, int n_in,
                              void* d_out, int out_size, void* d_ws, size_t ws_size,
                              hipStream_t stream) {
    const float4* hm4 = (const float4*)d_in[0];
    float4* out4 = (float4*)d_out;
    const int B = in_sizes[0] / NPIX;        // 131072
    const int blocks = (B + 15) / 16;        // 16 batches per 256-thread block
    nms_kernel<<<blocks, 256, 0, stream>>>(hm4, out4, B);
}

// Round 4
// 278.991 us; speedup vs baseline: 1.1252x; 1.0023x over previous
//
#include <hip/hip_runtime.h>

// NMS + farthest-pair + Voronoi masks, B=131072 heatmaps of 14x14 fp32.
// 4 batches per 64-lane wave (16 lanes = 1 DPP row per batch).
// Argmax = single u32-key max reduction (value<<8 | 255-flat): value-max and
// first-occurrence index in ONE 15+4-step reduction, pure VALU (DPP), no LDS.
// Survivors of (v > 0.6) lie in (0.6,1) -> fp32 exponent fixed at 126, so the
// 23-bit mantissa (+1) preserves exact float ordering in integer compare.

constexpr int L = 14;
constexpr int NPIX = L * L;   // 196
constexpr int NV4 = NPIX / 4; // 49

template <int CTRL>
__device__ __forceinline__ unsigned dpp_maxu(unsigned x) {
    unsigned y = (unsigned)__builtin_amdgcn_update_dpp(0, (int)x, CTRL, 0xF, 0xF, true);
    return x > y ? x : y;
}
__device__ __forceinline__ unsigned row_max16u(unsigned x) {
    x = dpp_maxu<0xB1>(x);   // quad_perm xor1
    x = dpp_maxu<0x4E>(x);   // quad_perm xor2
    x = dpp_maxu<0x141>(x);  // row_half_mirror
    x = dpp_maxu<0x140>(x);  // row_mirror
    return x;
}

__global__ __launch_bounds__(256) void nms_kernel(const float4* __restrict__ hm4,
                                                  float4* __restrict__ out4, int B) {
    const int lane = threadIdx.x & 63;
    const int s = lane & 15;
    const int b = blockIdx.x * 16 + ((threadIdx.x >> 6) << 2) + (lane >> 4);
    if (b >= B) return;

    const float4* __restrict__ bp = hm4 + (size_t)b * NV4;
    float4 a0 = bp[s];
    float4 a1 = bp[16 + s];
    float4 a2 = bp[32 + s];
    float4 a3 = make_float4(0.f, 0.f, 0.f, 0.f);   // sentinel slots = zero heat
    if (s == 0) a3 = bp[48];

    const float va[16] = {a0.x, a0.y, a0.z, a0.w, a1.x, a1.y, a1.z, a1.w,
                          a2.x, a2.y, a2.z, a2.w, a3.x, a3.y, a3.z, a3.w};

    // flat(slot i) = 4s + 64*(i>>2) + (i&3); sentinel flats 196..255 have
    // inv < 60 so they lose to every real zero-slot (inv >= 60). Low byte of
    // key is ALWAYS inv, so "suppress" == key &= 255.
    unsigned key[16];
    int xs[16], ys[16];
    const int s4 = s << 2;
#pragma unroll
    for (int i = 0; i < 16; ++i) {
        const int fl = s4 + ((i >> 2) << 6) + (i & 3);
        const int x = fl / L, y = fl - (fl / L) * L;
        xs[i] = x; ys[i] = y;
        const unsigned inv = 255u - (unsigned)fl;
        const unsigned kpos = (((__float_as_uint(va[i]) & 0x7FFFFFu) + 1u) << 8) | inv;
        key[i] = (va[i] > 0.6f) ? kpos : inv;
    }

    int peaks[4];
#pragma unroll
    for (int r = 0; r < 4; ++r) {
        unsigned mk = key[0];
#pragma unroll
        for (int i = 1; i < 16; ++i) mk = key[i] > mk ? key[i] : mk;
        mk = row_max16u(mk);
        const int flat = 255 - (int)(mk & 255u);
        peaks[r] = flat;
        if (r < 3) {
            // window [ax-5, ax+5) x [ay-5, ay+5); 0/15 clamps never bind for
            // x,y in [0,13]:  in <=> (unsigned)(x-(ax-5)) < 10
            const int ax = flat / L;
            const int bx = ax - 5;
            const int by = (flat - ax * L) - 5;
#pragma unroll
            for (int i = 0; i < 16; ++i) {
                const bool in = ((unsigned)(xs[i] - bx) < 10u) &
                                ((unsigned)(ys[i] - by) < 10u);
                key[i] = in ? (key[i] & 255u) : key[i];
            }
        }
    }

    int cx[4], cy[4];
#pragma unroll
    for (int i = 0; i < 4; ++i) {
        cx[i] = peaks[i] / L;
        cy[i] = peaks[i] - cx[i] * L;
    }

    // farthest pair among 6, first-index-wins argmax
    const int pa[6] = {0, 0, 0, 1, 1, 2};
    const int pb[6] = {1, 2, 3, 2, 3, 3};
    int bestd = -1, ax0 = 0, ay0 = 0, ax1 = 0, ay1 = 0;
#pragma unroll
    for (int p = 0; p < 6; ++p) {
        const int dx = cx[pb[p]] - cx[pa[p]];
        const int dy = cy[pb[p]] - cy[pa[p]];
        const int d = dx * dx + dy * dy;
        if (d > bestd) { bestd = d; ax0 = cx[pa[p]]; ay0 = cy[pa[p]];
                         ax1 = cx[pb[p]]; ay1 = cy[pb[p]]; }
    }

    // d1 < d2  <=>  2(ax1-ax0)x + 2(ay1-ay0)y < (ax1-ax0)(ax0+ax1)+(ay1-ay0)(ay0+ay1)
    const int Ax = (ax1 - ax0) * 2, Ay = (ay1 - ay0) * 2;
    const int K = (ax1 - ax0) * (ax0 + ax1) + (ay1 - ay0) * (ay0 + ay1);

    float m[16], n[16];
#pragma unroll
    for (int i = 0; i < 16; ++i) {
        const bool t = (Ax * xs[i] + Ay * ys[i]) < K;
        m[i] = t ? 1.0f : 0.0f;
        n[i] = t ? 0.0f : 1.0f;
    }

    float4* __restrict__ o1 = out4 + (size_t)b * NV4;
    float4* __restrict__ o2 = out4 + (size_t)(B + b) * NV4;
    o1[s]      = make_float4(m[0], m[1], m[2], m[3]);
    o1[16 + s] = make_float4(m[4], m[5], m[6], m[7]);
    o1[32 + s] = make_float4(m[8], m[9], m[10], m[11]);
    o2[s]      = make_float4(n[0], n[1], n[2], n[3]);
    o2[16 + s] = make_float4(n[4], n[5], n[6], n[7]);
    o2[32 + s] = make_float4(n[8], n[9], n[10], n[11]);
    if (s == 0) {
        o1[48] = make_float4(m[12], m[13], m[14], m[15]);
        o2[48] = make_float4(n[12], n[13], n[14], n[15]);
    }
}

extern "C" void kernel_launch(void* const* d_in, const int* in_sizes, int n_in,
                              void* d_out, int out_size, void* d_ws, size_t ws_size,
                              hipStream_t stream) {
    const float4* hm4 = (const float4*)d_in[0];
    float4* out4 = (float4*)d_out;
    const int B = in_sizes[0] / NPIX;        // 131072
    const int blocks = (B + 15) / 16;        // 16 batches per 256-thread block
    nms_kernel<<<blocks, 256, 0, stream>>>(hm4, out4, B);
}